// Round 5
// baseline (516.678 us; speedup 1.0000x reference)
//
#include <hip/hip_runtime.h>
#include <math.h>

typedef __attribute__((ext_vector_type(4))) float floatx4;
typedef __attribute__((ext_vector_type(8))) short shortx8;   // 8 bf16
typedef __attribute__((ext_vector_type(4))) short shortx4;   // 4 bf16 (8B)

#define NB 4
#define CC 768
#define WW 2048
#define HH 12
#define DD 64
#define GG 4
#define CG 192
#define HPG 3
#define KS 2                       // attention split-K factor
#define L2E 1.4426950408889634f
#define C18 0.18033688011112043f   // 0.125 * log2(e)
#define MSH 11.541560327111707f    // 8.0 * log2(e)  (fixed softmax shift)

__device__ __forceinline__ float fast_exp2(float x) {
    return __builtin_amdgcn_exp2f(x);   // v_exp_f32 (log2 domain)
}

__device__ __forceinline__ short f2bf(float f) {
    union { float f; unsigned u; } v; v.f = f;
    unsigned r = v.u + 0x7fffu + ((v.u >> 16) & 1u);   // RNE
    return (short)(r >> 16);
}
__device__ __forceinline__ float bf2f(short h) {
    union { unsigned u; float f; } v;
    v.u = ((unsigned)(unsigned short)h) << 16;
    return v.f;
}

template<int CTRL>
__device__ __forceinline__ float dppror(float v) {
    return __int_as_float(__builtin_amdgcn_update_dpp(
        0, __float_as_int(v), CTRL, 0xf, 0xf, false));
}
__device__ __forceinline__ float rsum16(float v) {   // 16-lane DPP-row sum
    v += dppror<0x128>(v);
    v += dppror<0x124>(v);
    v += dppror<0x122>(v);
    v += dppror<0x121>(v);
    return v;
}

// ---------------------------------------------------------------------------
// Prep 1: x [N,C,W] fp32 -> XTh/XTl [N,W,C] bf16 hi/lo (transpose + split).
// ---------------------------------------------------------------------------
__global__ __launch_bounds__(256) void prep_x(
    const float* __restrict__ x, short* __restrict__ XTh, short* __restrict__ XTl)
{
    const int w0 = blockIdx.x * 64;
    const int c0 = blockIdx.y * 64;
    const int n  = blockIdx.z;
    const int tid = threadIdx.x;
    const int w  = tid & 63;
    const int cb = c0 + (tid >> 6) * 16;

    float xv[16];
    #pragma unroll
    for (int j = 0; j < 16; ++j)
        xv[j] = x[((size_t)n * CC + cb + j) * WW + w0 + w];

    shortx8 hi0, hi1, lo0, lo1;
    #pragma unroll
    for (int j = 0; j < 8; ++j) {
        short h0 = f2bf(xv[j]);     hi0[j] = h0; lo0[j] = f2bf(xv[j]     - bf2f(h0));
        short h1 = f2bf(xv[j + 8]); hi1[j] = h1; lo1[j] = f2bf(xv[j + 8] - bf2f(h1));
    }
    const size_t ro = ((size_t)n * WW + w0 + w) * CC + cb;
    *(shortx8*)&XTh[ro]     = hi0;
    *(shortx8*)&XTh[ro + 8] = hi1;
    *(shortx8*)&XTl[ro]     = lo0;
    *(shortx8*)&XTl[ro + 8] = lo1;
}

// ---------------------------------------------------------------------------
// Prep 2: weights fp32 -> bf16 hi/lo, concat [mat][G,CG,CG].
// ---------------------------------------------------------------------------
#define WSZ (GG * CG * CG)   // 147456

__global__ __launch_bounds__(256) void prep_w(
    const float* __restrict__ wq, const float* __restrict__ wk,
    const float* __restrict__ wv, short* __restrict__ Wh, short* __restrict__ Wl)
{
    const int t = blockIdx.x * 256 + threadIdx.x;
    if (t >= WSZ) return;
    const float* src[3] = {wq, wk, wv};
    #pragma unroll
    for (int m = 0; m < 3; ++m) {
        float v = src[m][t];
        short h = f2bf(v);
        Wh[m * WSZ + t] = h;
        Wl[m * WSZ + t] = f2bf(v - bf2f(h));
    }
}

// ---------------------------------------------------------------------------
// Grouped 1x1 conv as bf16 hi/lo MFMA GEMM, one matrix (Q/K/V) per block.
// grid (W/64, G, 3*NB) with z = mat*NB + n.  No LDS, no barriers.
// ---------------------------------------------------------------------------
__global__ __launch_bounds__(256) void qkv_gemm(
    const short* __restrict__ XTh, const short* __restrict__ XTl,
    const short* __restrict__ Wh, const short* __restrict__ Wl,
    const float* __restrict__ bq, const float* __restrict__ bk,
    const float* __restrict__ bv,
    short* __restrict__ Qb, short* __restrict__ Kb, short* __restrict__ Vb)
{
    const int p0   = blockIdx.x * 64;
    const int g    = blockIdx.y;
    const int mat  = blockIdx.z >> 2;
    const int n    = blockIdx.z & 3;
    const int tid  = threadIdx.x;
    const int wid  = __builtin_amdgcn_readfirstlane(tid >> 6);
    const int lane = tid & 63;
    const int l15  = lane & 15;
    const int quad = lane >> 4;
    const int ob   = wid * 48;

    const short* xh = XTh + ((size_t)n * WW + p0 + l15) * CC + g * CG + quad * 8;
    const short* xl = XTl + ((size_t)n * WW + p0 + l15) * CC + g * CG + quad * 8;

    const short* whm = Wh + (size_t)mat * WSZ + ((size_t)g * CG + ob + l15) * CG + quad * 8;
    const short* wlm = Wl + (size_t)mat * WSZ + ((size_t)g * CG + ob + l15) * CG + quad * 8;

    floatx4 acc[3][4];
    #pragma unroll
    for (int mi = 0; mi < 3; ++mi)
        #pragma unroll
        for (int ni = 0; ni < 4; ++ni) acc[mi][ni] = (floatx4)0.0f;

    #pragma unroll
    for (int ks = 0; ks < 6; ++ks) {
        const int k0 = ks * 32;
        shortx8 ah[3], al[3], bh[4], bl[4];
        #pragma unroll
        for (int mi = 0; mi < 3; ++mi) {
            ah[mi] = *(const shortx8*)(whm + (size_t)mi * 16 * CG + k0);
            al[mi] = *(const shortx8*)(wlm + (size_t)mi * 16 * CG + k0);
        }
        #pragma unroll
        for (int ni = 0; ni < 4; ++ni) {
            bh[ni] = *(const shortx8*)(xh + (size_t)ni * 16 * CC + k0);
            bl[ni] = *(const shortx8*)(xl + (size_t)ni * 16 * CC + k0);
        }
        #pragma unroll
        for (int mi = 0; mi < 3; ++mi)
            #pragma unroll
            for (int ni = 0; ni < 4; ++ni) {
                acc[mi][ni] = __builtin_amdgcn_mfma_f32_16x16x32_bf16(ah[mi], bh[ni], acc[mi][ni], 0, 0, 0);
                acc[mi][ni] = __builtin_amdgcn_mfma_f32_16x16x32_bf16(ah[mi], bl[ni], acc[mi][ni], 0, 0, 0);
                acc[mi][ni] = __builtin_amdgcn_mfma_f32_16x16x32_bf16(al[mi], bh[ni], acc[mi][ni], 0, 0, 0);
            }
    }

    const float* bias = (mat == 0) ? bq : (mat == 1) ? bk : bv;
    short* Y = (mat == 0) ? Qb : (mat == 1) ? Kb : Vb;
    #pragma unroll
    for (int mi = 0; mi < 3; ++mi) {
        float4 b4 = *(const float4*)&bias[g * CG + ob + mi * 16 + quad * 4];
        const int o  = ob + mi * 16 + quad * 4;
        const int h  = g * HPG + (o >> 6);
        const int d0 = o & 63;
        const size_t nh = (size_t)n * HH + h;
        #pragma unroll
        for (int ni = 0; ni < 4; ++ni) {
            const int p = p0 + ni * 16 + l15;
            float y0 = acc[mi][ni][0] + b4.x;
            float y1 = acc[mi][ni][1] + b4.y;
            float y2 = acc[mi][ni][2] + b4.z;
            float y3 = acc[mi][ni][3] + b4.w;
            if (mat < 2) {
                shortx4 pk = { f2bf(y0), f2bf(y1), f2bf(y2), f2bf(y3) };
                *(shortx4*)&Y[(nh * WW + p) * DD + d0] = pk;   // [w][d]
            } else {
                const size_t vb = (nh * DD + d0) * WW + p;     // [d][w]
                Y[vb]          = f2bf(y0);
                Y[vb + WW]     = f2bf(y1);
                Y[vb + 2 * WW] = f2bf(y2);
                Y[vb + 3 * WW] = f2bf(y3);
            }
        }
    }
}

// ---------------------------------------------------------------------------
// Split-K attention. Block = (qtile 64, head, n, split). Each block scans
// WW/KS keys, accumulates unnormalized O (fixed-shift softmax) + l partials.
// No barriers; P via wave-private LDS strip; LDS total 9.2 KB -> 8 blocks/CU.
// grid ((W/64)*KS, H, N) with x = qt + 32*s (consecutive blocks share K/V).
// ---------------------------------------------------------------------------
#define PST 72

__global__ __launch_bounds__(256) void attn_split(
    const short* __restrict__ Qb, const short* __restrict__ Kb,
    const short* __restrict__ Vb, const float* __restrict__ mask,
    float* __restrict__ Op, float* __restrict__ lp)
{
    __shared__ __align__(16) short Pl[4 * 16 * PST];

    const int qt   = blockIdx.x & 31;
    const int s    = blockIdx.x >> 5;
    const int q0   = qt * 64;
    const int h    = blockIdx.y;
    const int n    = blockIdx.z;
    const int tid  = threadIdx.x;
    const int wid  = __builtin_amdgcn_readfirstlane(tid >> 6);
    const int lane = tid & 63;
    const int l15  = lane & 15;
    const int quad = lane >> 4;

    const size_t nh = (size_t)n * HH + h;
    const short* Kbase = Kb + nh * WW * DD;   // [key][d]
    const short* Vbase = Vb + nh * DD * WW;   // [d][w]
    const float* mbase = mask + (size_t)n * WW;
    const int ks0 = s * (WW / KS);

    shortx8 qf[2];
    {
        const short* qp = Qb + (nh * WW + q0 + wid * 16 + l15) * DD + quad * 8;
        qf[0] = *(const shortx8*)(qp);
        qf[1] = *(const shortx8*)(qp + 32);
    }

    floatx4 oacc[4];
    #pragma unroll
    for (int nn2 = 0; nn2 < 4; ++nn2) oacc[nn2] = (floatx4)0.0f;
    float lst[4] = {0.f, 0.f, 0.f, 0.f};

    short* Pw = Pl + wid * 16 * PST;

    for (int kt = 0; kt < WW / (64 * KS); ++kt) {
        const int k0 = ks0 + kt * 64;

        shortx8 kf[4][2], vf[4][2];
        #pragma unroll
        for (int jj = 0; jj < 4; ++jj) {
            const short* kp = Kbase + (size_t)(k0 + 16 * jj + l15) * DD + quad * 8;
            kf[jj][0] = *(const shortx8*)kp;
            kf[jj][1] = *(const shortx8*)(kp + 32);
        }
        #pragma unroll
        for (int nn2 = 0; nn2 < 4; ++nn2) {
            const short* vp = Vbase + (size_t)(nn2 * 16 + l15) * WW + k0 + quad * 8;
            vf[nn2][0] = *(const shortx8*)vp;
            vf[nn2][1] = *(const shortx8*)(vp + 32);
        }
        float mv2[4];
        #pragma unroll
        for (int jj = 0; jj < 4; ++jj)
            mv2[jj] = fmaf(mbase[k0 + 16 * jj + l15], L2E, -MSH);

        floatx4 sacc[4];
        #pragma unroll
        for (int jj = 0; jj < 4; ++jj) {
            sacc[jj] = (floatx4)0.0f;
            sacc[jj] = __builtin_amdgcn_mfma_f32_16x16x32_bf16(qf[0], kf[jj][0], sacc[jj], 0, 0, 0);
            sacc[jj] = __builtin_amdgcn_mfma_f32_16x16x32_bf16(qf[1], kf[jj][1], sacc[jj], 0, 0, 0);
        }

        // P = exp2(S * 0.125*log2e + (mask-8)*log2e)
        #pragma unroll
        for (int jj = 0; jj < 4; ++jj) {
            #pragma unroll
            for (int r = 0; r < 4; ++r) {
                float p = fast_exp2(fmaf(sacc[jj][r], C18, mv2[jj]));
                lst[r] += p;
                Pw[(quad * 4 + r) * PST + 16 * jj + l15] = f2bf(p);
            }
        }

        shortx8 pf0 = *(const shortx8*)&Pw[l15 * PST + quad * 8];
        shortx8 pf1 = *(const shortx8*)&Pw[l15 * PST + 32 + quad * 8];

        #pragma unroll
        for (int nn2 = 0; nn2 < 4; ++nn2) {
            oacc[nn2] = __builtin_amdgcn_mfma_f32_16x16x32_bf16(pf0, vf[nn2][0], oacc[nn2], 0, 0, 0);
            oacc[nn2] = __builtin_amdgcn_mfma_f32_16x16x32_bf16(pf1, vf[nn2][1], oacc[nn2], 0, 0, 0);
        }
    }

    // store raw partials: O (fp32, [nh][s][q][d]) and l ([nh][s][q])
    float* obase = Op + ((nh * KS + s) * WW + q0) * DD;
    #pragma unroll
    for (int nn2 = 0; nn2 < 4; ++nn2)
        #pragma unroll
        for (int r = 0; r < 4; ++r)
            obase[(size_t)(wid * 16 + quad * 4 + r) * DD + nn2 * 16 + l15] = oacc[nn2][r];

    #pragma unroll
    for (int r = 0; r < 4; ++r) lst[r] = rsum16(lst[r]);
    if (l15 == 0) {
        float* lbase = lp + (nh * KS + s) * WW + q0;
        #pragma unroll
        for (int r = 0; r < 4; ++r) lbase[wid * 16 + quad * 4 + r] = lst[r];
    }
}

// ---------------------------------------------------------------------------
// Reduce: sum KS partials, normalize, transpose to [N,C,W].
// grid (W/64, H, N), block 256.
// ---------------------------------------------------------------------------
#define RST 65

__global__ __launch_bounds__(256) void attn_reduce(
    const float* __restrict__ Op, const float* __restrict__ lp,
    float* __restrict__ out)
{
    __shared__ float Ol[64 * RST];   // [q][d], stride 65
    __shared__ float linv[64];

    const int q0 = blockIdx.x * 64;
    const int h  = blockIdx.y;
    const int n  = blockIdx.z;
    const int tid = threadIdx.x;
    const size_t nh = (size_t)n * HH + h;

    if (tid < 64) {
        float ls = 0.f;
        #pragma unroll
        for (int s = 0; s < KS; ++s) ls += lp[(nh * KS + s) * WW + q0 + tid];
        linv[tid] = 1.0f / ls;
    }
    __syncthreads();

    #pragma unroll
    for (int it = 0; it < 4; ++it) {
        const int idx = tid + it * 256;        // 64 q x 16 d-groups, dg fast
        const int q  = idx >> 4;
        const int d0 = (idx & 15) * 4;
        floatx4 a = (floatx4)0.0f;
        #pragma unroll
        for (int s = 0; s < KS; ++s)
            a += *(const floatx4*)&Op[(((nh * KS + s) * WW) + q0 + q) * DD + d0];
        a *= linv[q];
        #pragma unroll
        for (int i = 0; i < 4; ++i) Ol[q * RST + d0 + i] = a[i];
    }
    __syncthreads();

    float* obase = out + (nh * DD) * WW + q0;
    #pragma unroll
    for (int it = 0; it < 4; ++it) {
        const int idx = tid + it * 256;        // 64 d x 16 q-groups, qg fast
        const int q4 = (idx & 15) * 4;
        const int d  = idx >> 4;
        floatx4 v;
        #pragma unroll
        for (int i = 0; i < 4; ++i) v[i] = Ol[(q4 + i) * RST + d];
        *(floatx4*)&obase[(size_t)d * WW + q4] = v;
    }
}

// ---------------------------------------------------------------------------
extern "C" void kernel_launch(void* const* d_in, const int* in_sizes, int n_in,
                              void* d_out, int out_size, void* d_ws, size_t ws_size,
                              hipStream_t stream) {
    const float* x    = (const float*)d_in[0];
    const float* mask = (const float*)d_in[1];
    const float* wq   = (const float*)d_in[2];
    const float* bq   = (const float*)d_in[3];
    const float* wk   = (const float*)d_in[4];
    const float* bk   = (const float*)d_in[5];
    const float* wv   = (const float*)d_in[6];
    const float* bv   = (const float*)d_in[7];
    float* out = (float*)d_out;

    const size_t per = (size_t)NB * HH * WW * DD;   // 6,291,456
    short* Qb  = (short*)d_ws;
    short* Kb  = Qb + per;
    short* Vb  = Kb + per;
    // prep region (dead after qkv_gemm):
    short* XTh = Vb + per;
    short* XTl = XTh + per;
    short* Whp = XTl + per;
    short* Wlp = Whp + 3 * WSZ;
    // attention partials overlay the prep region:
    float* Op  = (float*)(Vb + per);                // KS*per fp32
    float* lp  = Op + (size_t)KS * per;             // KS*N*H*W fp32

    hipLaunchKernelGGL(prep_x, dim3(WW / 64, CC / 64, NB), dim3(256), 0, stream,
                       x, XTh, XTl);
    hipLaunchKernelGGL(prep_w, dim3((WSZ + 255) / 256), dim3(256), 0, stream,
                       wq, wk, wv, Whp, Wlp);
    hipLaunchKernelGGL(qkv_gemm, dim3(WW / 64, GG, 3 * NB), dim3(256), 0, stream,
                       XTh, XTl, Whp, Wlp, bq, bk, bv, Qb, Kb, Vb);
    hipLaunchKernelGGL(attn_split, dim3((WW / 64) * KS, HH, NB), dim3(256), 0, stream,
                       Qb, Kb, Vb, mask, Op, lp);
    hipLaunchKernelGGL(attn_reduce, dim3(WW / 64, HH, NB), dim3(256), 0, stream,
                       Op, lp, out);
}